// Round 2
// baseline (103.013 us; speedup 1.0000x reference)
//
#include <hip/hip_runtime.h>
#include <hip/hip_fp16.h>

#define HH 128
#define WW 128
#define CC 64
#define OO 64
#define HWSZ (HH*WW)

typedef _Float16 f16x8 __attribute__((ext_vector_type(8)));
typedef _Float16 f16x4 __attribute__((ext_vector_type(4)));
typedef float    f32x4 __attribute__((ext_vector_type(4)));

__device__ __forceinline__ unsigned short f2h(float f) {
    return __half_as_ushort(__float2half_rn(f));
}

// ---------------------------------------------------------------------------
// K0: prep_all. z<4: x NCHW fp32 -> NHWC fp16 (LDS-tiled transpose).
//     z==4: weight repack -> fp16 in MFMA B-fragment-major order (16x16x32):
//       wdtf[kc(18)][nt(4)][lane(64)][j(8)] : o=nt*16+(l&15), c=(kc&1)*32+((l>>4)&3)*8+j, k=kc>>1
//       wotf[kc(18)][nt(2)][lane(64)][j(8)] : same, oc>=18 zero-padded
// ---------------------------------------------------------------------------
__global__ __launch_bounds__(256) void prep_all(const float* __restrict__ x,
                                                const float* __restrict__ wd,
                                                const float* __restrict__ wo,
                                                unsigned short* __restrict__ xh,
                                                unsigned short* __restrict__ wdtf,
                                                unsigned short* __restrict__ wotf) {
    int t = threadIdx.x;
    if (blockIdx.z == 4) {
        int i = (blockIdx.y * 2 + blockIdx.x) * 256 + t;
        if (i < 36864) {
            int j = i & 7, l = (i >> 3) & 63, nt = (i >> 9) & 3, kcb = i >> 11;
            int k = kcb >> 1, cb = kcb & 1;
            int o = nt * 16 + (l & 15);
            int c = cb * 32 + ((l >> 4) & 3) * 8 + j;
            wdtf[i] = f2h(wd[(o * 64 + c) * 9 + k]);
        } else if (i < 36864 + 18432) {
            int jdx = i - 36864;
            int j = jdx & 7, l = (jdx >> 3) & 63, nt = (jdx >> 9) & 1, kcb = jdx >> 10;
            int k = kcb >> 1, cb = kcb & 1;
            int oc = nt * 16 + (l & 15);
            int c = cb * 32 + ((l >> 4) & 3) * 8 + j;
            wotf[jdx] = f2h(oc < 18 ? wo[(oc * 64 + c) * 9 + k] : 0.0f);
        }
        return;
    }
    __shared__ float tile[64 * 65];
    int w0 = blockIdx.x * 64, h = blockIdx.y, b = blockIdx.z;
    const float* xb = x + ((long)b * CC * HWSZ) + h * WW + w0;
#pragma unroll
    for (int i = 0; i < 16; ++i) {
        int idx = i * 256 + t; int c = idx >> 6, w = idx & 63;
        tile[c * 65 + w] = xb[c * HWSZ + w];
    }
    __syncthreads();
    unsigned short* xo = xh + ((long)((b * HH + h) * WW + w0)) * CC;
#pragma unroll
    for (int i = 0; i < 8; ++i) {
        int idx = i * 256 + t; int w = idx >> 5, c = (idx & 31) * 2;
        ushort2 u;
        u.x = f2h(tile[c * 65 + w]);
        u.y = f2h(tile[(c + 1) * 65 + w]);
        *(ushort2*)(xo + w * CC + c) = u;
    }
}

// ---------------------------------------------------------------------------
// K1: fused offset+deform conv.  R11: software-pipelined phase B.
//   R10 post-mortem: 3->4 blocks/CU was NEUTRAL -> blocks convoy in
//   lockstep; gather latency is exposed INSIDE each block's serial
//   sample -> vmcnt(0) -> barrier -> MFMA chain. Fix: double-buffered
//   3-k segments; segment s+1's 12 gathers are ISSUED before segment
//   s's MFMA cluster, and the vmcnt wait + bilinear + ds_write land
//   after it (T14 issue-early/write-late). One barrier per segment;
//   pipeline runs across the g2 boundary. Gather latency (~300-600cy
//   L2) hides under ds_read+MFMA+B-frag loads (~250cy) + cross-wave.
// LDS: union(xr 29.4KB, bufA+bufB 25.6KB) + offs 4.6KB = 34.0KB -> 4 blocks/CU.
// VGPR: ~48 in-flight samples + 6 packed weights live across MFMA; cap 128.
// ---------------------------------------------------------------------------
#define VST3 200  // seg buffer row stride (ushorts): 3*64 + 8 pad; word stride 100 -> (m+q)%8 banks, same class as R9's 328
#define OST 18    // offs row stride (floats)

struct Samp { f16x8 s0, s1, s2, s3; f16x4 w; };

template<int G2, int K0>
__device__ __forceinline__ void issue3(const unsigned short* __restrict__ xb,
                                       const float* __restrict__ offs,
                                       int h, int w0, int spx, int ch8, Samp (&S)[3]) {
    const float* oprow = &offs[(G2 * 32 + spx) * OST];
    int wpx = w0 + G2 * 32 + spx;
#pragma unroll
    for (int ki = 0; ki < 3; ++ki) {
        int k = K0 + ki;
        int ky = k / 3, kx = k - ky * 3;
        float2 ov = *(const float2*)(oprow + 2 * k);
        float py  = (float)(h + ky - 1) + ov.x;
        float pxf = (float)(wpx + kx - 1) + ov.y;
        float y0f = floorf(py), x0f = floorf(pxf);
        float wy = py - y0f, wx = pxf - x0f;
        int y0 = (int)y0f, x0 = (int)x0f, y1 = y0 + 1, x1 = x0 + 1;
        bool vy0 = (unsigned)y0 < HH, vy1 = (unsigned)y1 < HH;
        bool vx0 = (unsigned)x0 < WW, vx1 = (unsigned)x1 < WW;
        int y0c = min(max(y0, 0), HH - 1), y1c = min(max(y1, 0), HH - 1);
        int x0c = min(max(x0, 0), WW - 1), x1c = min(max(x1, 0), WW - 1);
        f16x4 w4;
        w4[0] = (_Float16)((vy0 && vx0) ? (1.f - wy) * (1.f - wx) : 0.f);
        w4[1] = (_Float16)((vy0 && vx1) ? (1.f - wy) * wx : 0.f);
        w4[2] = (_Float16)((vy1 && vx0) ? wy * (1.f - wx) : 0.f);
        w4[3] = (_Float16)((vy1 && vx1) ? wy * wx : 0.f);
        S[ki].s0 = *(const f16x8*)(xb + (y0c * WW + x0c) * CC + ch8);
        S[ki].s1 = *(const f16x8*)(xb + (y0c * WW + x1c) * CC + ch8);
        S[ki].s2 = *(const f16x8*)(xb + (y1c * WW + x0c) * CC + ch8);
        S[ki].s3 = *(const f16x8*)(xb + (y1c * WW + x1c) * CC + ch8);
        S[ki].w = w4;
    }
}

__device__ __forceinline__ void finish3(Samp (&S)[3], unsigned short* __restrict__ buf,
                                        int spx, int ch8) {
#pragma unroll
    for (int ki = 0; ki < 3; ++ki) {
        f16x8 a = S[ki].s0 * S[ki].w[0] + S[ki].s1 * S[ki].w[1]
                + S[ki].s2 * S[ki].w[2] + S[ki].s3 * S[ki].w[3];   // v_pk_fma_f16
        *(f16x8*)&buf[spx * VST3 + ki * 64 + ch8] = a;
    }
}

template<int K0>
__device__ __forceinline__ void mfma3(const unsigned short* __restrict__ buf,
                                      const unsigned short* __restrict__ wdtf,
                                      int m, int q, int wv, int l,
                                      f32x4& acc0, f32x4& acc1) {
    __builtin_amdgcn_s_setprio(1);
#pragma unroll
    for (int ki = 0; ki < 3; ++ki) {
        const unsigned short* vs = &buf[m * VST3 + ki * 64 + q * 8];
        f16x8 a00 = *(const f16x8*)(vs);
        f16x8 a01 = *(const f16x8*)(vs + 32);
        f16x8 a10 = *(const f16x8*)(vs + 16 * VST3);
        f16x8 a11 = *(const f16x8*)(vs + 16 * VST3 + 32);
        int kcg = (K0 + ki) * 2;
        f16x8 b0 = *(const f16x8*)(wdtf + (kcg * 4 + wv) * 512 + l * 8);
        f16x8 b1 = *(const f16x8*)(wdtf + ((kcg + 1) * 4 + wv) * 512 + l * 8);
        acc0 = __builtin_amdgcn_mfma_f32_16x16x32_f16(a00, b0, acc0, 0, 0, 0);
        acc1 = __builtin_amdgcn_mfma_f32_16x16x32_f16(a10, b0, acc1, 0, 0, 0);
        acc0 = __builtin_amdgcn_mfma_f32_16x16x32_f16(a01, b1, acc0, 0, 0, 0);
        acc1 = __builtin_amdgcn_mfma_f32_16x16x32_f16(a11, b1, acc1, 0, 0, 0);
    }
    __builtin_amdgcn_s_setprio(0);
}

__global__ __launch_bounds__(256, 4) void fused_dcn(const unsigned short* __restrict__ xh,
                                                    const unsigned short* __restrict__ wotf,
                                                    const float* __restrict__ b_off,
                                                    const unsigned short* __restrict__ wdtf,
                                                    const float* __restrict__ b_dcn,
                                                    float* __restrict__ out) {
    __shared__ __attribute__((aligned(16))) unsigned short shm[3 * 68 * 72]; // union: xr 29376B >= bufA+bufB 25600B
    __shared__ __attribute__((aligned(16))) float offs[64 * OST];
    unsigned short* xr   = shm;          // phase A: [row(3)][px(66,pad68)][ch(64,pad72)]
    unsigned short* bufA = shm;          // phase B seg buffers: [px(32)][3*64 pad VST3]
    unsigned short* bufB = shm + 32 * VST3;

    // ---- XCD-locality decode ----
    int id = blockIdx.x;
    int c8 = id & 7;           // XCD class
    int j  = id >> 3;
    int g  = (j >> 5) * 8 + c8;        // group 0..31 = b*8 + (h>>4)
    int inner = j & 31;
    int b  = g >> 3;
    int h  = (g & 7) * 16 + (inner >> 1);
    int w0 = (inner & 1) * 64;

    int t = threadIdx.x;
    int l = t & 63, wv = t >> 6;
    int m = l & 15, q = l >> 4;

    // ================= phase A: offset conv =================
#pragma unroll
    for (int i = 0; i < 7; ++i) {
        int idx = i * 256 + t;
        if (idx < 1584) {
            int r = idx / 528;
            int rem = idx - r * 528;
            int p = rem >> 3, cc = rem & 7;
            int y = h + r - 1, wx = w0 - 1 + p;
            uint4 v = make_uint4(0u, 0u, 0u, 0u);
            if (((unsigned)y < HH) && ((unsigned)wx < WW))
                v = *(const uint4*)(xh + ((long)((b * HH + y) * WW + wx)) * CC + cc * 8);
            *(uint4*)&xr[(r * 68 + p) * 72 + cc * 8] = v;
        }
    }
    __syncthreads();
    {
        int px0 = wv * 16;
        f32x4 acc0 = {0.f, 0.f, 0.f, 0.f}, acc1 = {0.f, 0.f, 0.f, 0.f};
#pragma unroll
        for (int k = 0; k < 9; ++k) {
            int ky = k / 3, kx = k - ky * 3;
            const unsigned short* ar = &xr[(ky * 68 + px0 + m + kx) * 72 + q * 8];
            f16x8 a0 = *(const f16x8*)(ar);
            f16x8 a1 = *(const f16x8*)(ar + 32);
            const unsigned short* bk = wotf + (k * 2) * 2 * 512 + l * 8;
            f16x8 b00 = *(const f16x8*)(bk);
            f16x8 b01 = *(const f16x8*)(bk + 512);
            f16x8 b10 = *(const f16x8*)(bk + 1024);
            f16x8 b11 = *(const f16x8*)(bk + 1536);
            acc0 = __builtin_amdgcn_mfma_f32_16x16x32_f16(a0, b00, acc0, 0, 0, 0);
            acc0 = __builtin_amdgcn_mfma_f32_16x16x32_f16(a1, b10, acc0, 0, 0, 0);
            acc1 = __builtin_amdgcn_mfma_f32_16x16x32_f16(a0, b01, acc1, 0, 0, 0);
            acc1 = __builtin_amdgcn_mfma_f32_16x16x32_f16(a1, b11, acc1, 0, 0, 0);
        }
        float bo0 = b_off[m];
#pragma unroll
        for (int r = 0; r < 4; ++r)
            offs[(px0 + q * 4 + r) * OST + m] = acc0[r] + bo0;
        if (m < 2) {
            float bo1 = b_off[16 + m];
#pragma unroll
            for (int r = 0; r < 4; ++r)
                offs[(px0 + q * 4 + r) * OST + 16 + m] = acc1[r] + bo1;
        }
    }
    __syncthreads();   // offs ready; xr dead; seg buffers may now overwrite shm

    // ================= phase B: deform conv (pipelined 6x3-k segments) =====
    int spx = t >> 3, ch8 = (t & 7) * 8;    // sampler: pixel 0..31, 16B chunk

    const unsigned short* xb = xh + (long)b * HWSZ * CC;
    int o = wv * 16 + m;
    float bo = b_dcn[o];
    float* outo = out + ((long)(b * OO + o)) * HWSZ + h * WW;

    Samp S[3];
    f32x4 acc0 = {0.f, 0.f, 0.f, 0.f}, acc1 = {0.f, 0.f, 0.f, 0.f};

    // step 0: prologue (no MFMA to overlap)
    issue3<0, 0>(xb, offs, h, w0, spx, ch8, S);
    finish3(S, bufA, spx, ch8);
    __syncthreads();

    // step 1
    issue3<0, 3>(xb, offs, h, w0, spx, ch8, S);
    mfma3<0>(bufA, wdtf, m, q, wv, l, acc0, acc1);
    finish3(S, bufB, spx, ch8);
    __syncthreads();

    // step 2
    issue3<0, 6>(xb, offs, h, w0, spx, ch8, S);
    mfma3<3>(bufB, wdtf, m, q, wv, l, acc0, acc1);
    finish3(S, bufA, spx, ch8);
    __syncthreads();

    // step 3 (crosses g2 boundary: issue for right half while finishing left)
    issue3<1, 0>(xb, offs, h, w0, spx, ch8, S);
    mfma3<6>(bufA, wdtf, m, q, wv, l, acc0, acc1);
    {
        f32x4 r0 = acc0, r1 = acc1;
        r0[0] += bo; r0[1] += bo; r0[2] += bo; r0[3] += bo;
        r1[0] += bo; r1[1] += bo; r1[2] += bo; r1[3] += bo;
        *(f32x4*)(outo + w0 + q * 4) = r0;
        *(f32x4*)(outo + w0 + 16 + q * 4) = r1;
        acc0 = f32x4{0.f, 0.f, 0.f, 0.f};
        acc1 = f32x4{0.f, 0.f, 0.f, 0.f};
    }
    finish3(S, bufB, spx, ch8);
    __syncthreads();

    // step 4
    issue3<1, 3>(xb, offs, h, w0, spx, ch8, S);
    mfma3<0>(bufB, wdtf, m, q, wv, l, acc0, acc1);
    finish3(S, bufA, spx, ch8);
    __syncthreads();

    // step 5
    issue3<1, 6>(xb, offs, h, w0, spx, ch8, S);
    mfma3<3>(bufA, wdtf, m, q, wv, l, acc0, acc1);
    finish3(S, bufB, spx, ch8);
    __syncthreads();

    // step 6: epilogue
    mfma3<6>(bufB, wdtf, m, q, wv, l, acc0, acc1);
    {
        f32x4 r0 = acc0, r1 = acc1;
        r0[0] += bo; r0[1] += bo; r0[2] += bo; r0[3] += bo;
        r1[0] += bo; r1[1] += bo; r1[2] += bo; r1[3] += bo;
        *(f32x4*)(outo + w0 + 32 + q * 4) = r0;
        *(f32x4*)(outo + w0 + 48 + q * 4) = r1;
    }
}

// ---------------------------------------------------------------------------
extern "C" void kernel_launch(void* const* d_in, const int* in_sizes, int n_in,
                              void* d_out, int out_size, void* d_ws, size_t ws_size,
                              hipStream_t stream) {
    const float* x     = (const float*)d_in[0];
    const float* w_off = (const float*)d_in[1];
    const float* b_off = (const float*)d_in[2];
    const float* w_dcn = (const float*)d_in[3];
    const float* b_dcn = (const float*)d_in[4];
    float* out = (float*)d_out;

    char* ws = (char*)d_ws;
    unsigned short* xh   = (unsigned short*)ws;              //  8,388,608 B
    unsigned short* wdtf = (unsigned short*)(ws + 8388608);  //     73,728 B
    unsigned short* wotf = (unsigned short*)(ws + 8462336);  //     36,864 B

    hipLaunchKernelGGL(prep_all, dim3(2, 128, 5), dim3(256), 0, stream,
                       x, w_dcn, w_off, xh, wdtf, wotf);
    hipLaunchKernelGGL(fused_dcn, dim3(1024), dim3(256), 0, stream,
                       xh, wotf, b_off, wdtf, b_dcn, out);
}